// Round 1
// baseline (262.999 us; speedup 1.0000x reference)
//
#include <hip/hip_runtime.h>

// Problem constants (from reference setup_inputs)
constexpr int N = 2, C = 256, T = 16, H = 56, W = 56, K = 5, OUTP = 16;
constexpr int ROI_TOTAL  = N * T * K * C * OUTP * OUTP;  // 10,485,760
constexpr int FEAT_TOTAL = N * C * T * H * W;            // 25,690,112

// roi_feats[n][t][k][c][py][px] : one thread per output element.
// Index layout: idx = ((((n*T + t)*K + k)*C + c)*OUT + py)*OUT + px
// C*OUT*OUT = 65536, so (n,t,k) = idx>>16 and (c,py,px) = low 16 bits.
__global__ __launch_bounds__(256) void roi_align_kernel(
    const float* __restrict__ feat,
    const float* __restrict__ rois,
    float* __restrict__ out)
{
    int idx = blockIdx.x * 256 + threadIdx.x;
    if (idx >= ROI_TOTAL) return;

    int px = idx & 15;
    int py = (idx >> 4) & 15;
    int c  = (idx >> 8) & 255;
    int rest = idx >> 16;          // (n*T + t)*K + k, range [0,160)
    int k  = rest % 5;
    int nt = rest / 5;             // n*T + t
    int t  = nt & 15;
    int n  = nt >> 4;

    // box -> continuous coords (aligned=True: -0.5)
    const float* r = rois + (n * K + k) * 5;
    float bx1 = r[1] * (1.0f / 16.0f) - 0.5f;
    float by1 = r[2] * (1.0f / 16.0f) - 0.5f;
    float bx2 = r[3] * (1.0f / 16.0f) - 0.5f;
    float by2 = r[4] * (1.0f / 16.0f) - 0.5f;
    float bw = (bx2 - bx1) * (1.0f / 16.0f);   // bin width
    float bh = (by2 - by1) * (1.0f / 16.0f);   // bin height

    const float* fp = feat + ((size_t)((n * C + c) * T + t)) * (H * W);

    float acc = 0.0f;
    #pragma unroll
    for (int gy = 0; gy < 2; ++gy) {
        float Yf = by1 + ((float)py + (gy ? 0.75f : 0.25f)) * bh;
        #pragma unroll
        for (int gx = 0; gx < 2; ++gx) {
            float Xf = bx1 + ((float)px + (gx ? 0.75f : 0.25f)) * bw;
            // strict inequalities, matching reference `valid`
            if (Yf > -1.0f && Yf < (float)H && Xf > -1.0f && Xf < (float)W) {
                float Yc = fminf(fmaxf(Yf, 0.0f), (float)(H - 1));
                float Xc = fminf(fmaxf(Xf, 0.0f), (float)(W - 1));
                int y0 = (int)Yc;                 // floor (Yc >= 0)
                int x0 = (int)Xc;
                int y1i = min(y0 + 1, H - 1);
                int x1i = min(x0 + 1, W - 1);
                float ly = Yc - (float)y0;
                float lx = Xc - (float)x0;
                float hy = 1.0f - ly;
                float hx = 1.0f - lx;
                const float* row0 = fp + y0  * W;
                const float* row1 = fp + y1i * W;
                acc += row0[x0]  * hy * hx
                     + row0[x1i] * hy * lx
                     + row1[x0]  * ly * hx
                     + row1[x1i] * ly * lx;
            }
        }
    }
    out[idx] = acc * 0.25f;   // mean over 2x2 sampling grid
}

extern "C" void kernel_launch(void* const* d_in, const int* in_sizes, int n_in,
                              void* d_out, int out_size, void* d_ws, size_t ws_size,
                              hipStream_t stream)
{
    const float* feat = (const float*)d_in[0];
    const float* rois = (const float*)d_in[1];
    // d_in[2] = entity_mask: unused by the reference computation.

    float* roi_out  = (float*)d_out;               // 10,485,760 floats
    float* feat_out = (float*)d_out + ROI_TOTAL;   // 25,690,112 floats

    // Output 1: identity passthrough of feat (D2D DMA, graph-capture safe).
    hipMemcpyAsync(feat_out, feat, (size_t)FEAT_TOTAL * sizeof(float),
                   hipMemcpyDeviceToDevice, stream);

    // Output 0: RoIAlign.
    roi_align_kernel<<<ROI_TOTAL / 256, 256, 0, stream>>>(feat, rois, roi_out);
}